// Round 20
// baseline (369.825 us; speedup 1.0000x reference)
//
#include <hip/hip_runtime.h>
#include <hip/hip_bf16.h>
#include <hip/hip_fp16.h>

#define NMAX   100000
#define EMAX   1600000
#define NGRAPH 256
#define DIN    192
#define HDIM   64
#define DOUTD  32
#define NCLS   2
#define TNI    64          // node tile for dense kernels
#define FP     72          // f16 LDS pitch ([64][72]: 144B rows, 2-way bank alias)
#define NB_SHIFT 8                          // 256 nodes per bucket
#define NBUCK  ((NMAX >> NB_SHIFT) + 1)     // 391
#define T1E    2048                         // edges per stage super-tile
#define P2CAP  15872                        // phase-2 LDS col capacity (62 KB)
#define WT_W1  (64 * DIN)                   // g_wT offset of W1^T
#define WT_W2  (64 * DIN + 64 * HDIM)       // g_wT offset of W2^T

typedef float    f2v  __attribute__((ext_vector_type(2)));
typedef float    f32x4 __attribute__((ext_vector_type(4)));
typedef _Float16 h4   __attribute__((ext_vector_type(4)));

// All scratch in device globals — no dependence on d_ws / ws_size.
// g_bcnt / g_cc are zeroed by k_meta AFTER use each run (self-repoison;
// first run relies on .bss zero-init).
__device__ float         g_dis[NMAX];
__device__ float         g_h[NMAX * HDIM];   // activations (gather output)
__device__ unsigned char g_t8[NMAX * HDIM];  // fp8 e4m3 messages, ROW-major (64B/row)
__device__ int           g_row[NMAX + 1];    // CSR row pointers
__device__ int           g_col[2 * EMAX];    // CSR neighbor lists
__device__ unsigned      g_stage[2 * EMAX];  // PACKED staging: (dest&255)<<24 | src
__device__ int           g_bcnt[NBUCK];      // per-bucket pair counts
__device__ int           g_bbase[NBUCK + 1]; // bucket base offsets (excl scan)
__device__ int           g_bcur[NBUCK];      // bucket fill cursors
__device__ int           g_gptr[NGRAPH + 1]; // per-graph node ranges (batch sorted)
__device__ int           g_cc;
__device__ int           g_flag;             // 0 = (2,E) contiguous, 1 = (E,2) interleaved
__device__ _Float16      g_wT[64 * DIN + 2 * 64 * HDIM];  // pre-transposed f16 weights

// PLAIN loads: ei is re-read by k_stage after k_count — let it fill L2/L3.
__device__ __forceinline__ void load_edge(const int* __restrict__ ei, int E, int e,
                                          int& s, int& d) {
    if (g_flag) { s = ei[2 * e]; d = ei[2 * e + 1]; }
    else        { s = ei[e];     d = ei[e + E];     }
}

// one-time weight transpose to f16 [nn][kk] layout (feeds MFMA B-operand)
__global__ void k_wprep(const float* __restrict__ Win, const float* __restrict__ W1,
                        const float* __restrict__ W2) {
    int i = blockIdx.x * 256 + threadIdx.x;
    if (i < WT_W1) {
        int nn = i / DIN, kk = i - nn * DIN;
        g_wT[i] = (_Float16)Win[(size_t)kk * HDIM + nn];
    } else if (i < WT_W2) {
        int j = i - WT_W1;
        int nn = j >> 6, kk = j & 63;
        g_wT[i] = (_Float16)W1[(size_t)kk * HDIM + nn];
    } else if (i < WT_W2 + 64 * HDIM) {
        int j = i - WT_W2;
        int nn = j >> 6, kk = j & 63;
        g_wT[i] = (_Float16)W2[(size_t)kk * HDIM + nn];
    }
}

// fused: self-loop layout-detect + LDS-privatized 391-bin bucket histogram.
__global__ __launch_bounds__(256) void k_count(const int* __restrict__ ei, int E) {
    __shared__ int hcnt[NBUCK];
    for (int b = threadIdx.x; b < NBUCK; b += 256) hcnt[b] = 0;
    __syncthreads();
    int stride = gridDim.x * 256;
    for (int e = blockIdx.x * 256 + threadIdx.x; e < E; e += stride) {
        int a = ei[e];
        int c = ei[e + E];
        if (a == c) atomicAdd(&g_cc, 1);
        atomicAdd(&hcnt[a >> NB_SHIFT], 1);
        atomicAdd(&hcnt[c >> NB_SHIFT], 1);
    }
    __syncthreads();
    for (int b = threadIdx.x; b < NBUCK; b += 256) {
        int v = hcnt[b];
        if (v) atomicAdd(&g_bcnt[b], v);
    }
}

// merged: block 0 = bucket scan (bases/cursors/flag, then SELF-ZERO the
// accumulators for the next run); blocks 1.. = graph pointers
__global__ __launch_bounds__(512) void k_meta(const int* __restrict__ batch, int n) {
    __shared__ int sh[512];
    int tid = threadIdx.x;
    if (blockIdx.x == 0) {
        int c = (tid < NBUCK) ? g_bcnt[tid] : 0;
        sh[tid] = c;
        __syncthreads();
        for (int off = 1; off < 512; off <<= 1) {
            int t = (tid >= off) ? sh[tid - off] : 0;
            __syncthreads();
            sh[tid] += t;
            __syncthreads();
        }
        if (tid < NBUCK) {
            int base = sh[tid] - c;     // exclusive
            g_bbase[tid] = base;
            g_bcur[tid]  = base;
            g_bcnt[tid]  = 0;           // re-poison for next run
        }
        if (tid == NBUCK - 1) g_bbase[NBUCK] = sh[tid];
        if (tid == 0) { g_flag = (g_cc != 0) ? 1 : 0; g_cc = 0; }
    } else {
        int i = (blockIdx.x - 1) * 512 + tid;
        if (i > n) return;
        if (i == 0) {
            int b0 = batch[0];
            for (int g = 0; g <= b0; ++g) g_gptr[g] = 0;
        } else if (i == n) {
            int bl = batch[n - 1];
            for (int g = bl + 1; g <= NGRAPH; ++g) g_gptr[g] = n;
        } else {
            int bp = batch[i - 1], bc = batch[i];
            for (int g = bp + 1; g <= bc; ++g) g_gptr[g] = i;
        }
    }
}

// ---- phase 1: stage endpoint pairs grouped by 256-node bucket ----
// 512 threads; global stage entries PACKED 4B: (dest&255)<<24 | src (src < 2^24)
__global__ __launch_bounds__(512) void k_stage(const int* __restrict__ ei, int E) {
    __shared__ int2 sbuf[2 * T1E];           // 4096 pairs, 32 KB
    __shared__ int  scnt[NBUCK], soff[NBUCK], sput[NBUCK], sbase[NBUCK];
    __shared__ int  sc[512];
    int tid = threadIdx.x;
    int e0  = blockIdx.x * T1E;
    for (int b = tid; b < NBUCK; b += 512) { scnt[b] = 0; sput[b] = 0; }
    __syncthreads();

    int s[4], d[4];
    #pragma unroll
    for (int it = 0; it < 4; ++it) {
        int e = e0 + it * 512 + tid;
        if (e < E) {
            load_edge(ei, E, e, s[it], d[it]);
            atomicAdd(&scnt[d[it] >> NB_SHIFT], 1);
            atomicAdd(&scnt[s[it] >> NB_SHIFT], 1);
        } else s[it] = -1;
    }
    __syncthreads();

    sc[tid] = (tid < NBUCK) ? scnt[tid] : 0;
    __syncthreads();
    for (int off = 1; off < 512; off <<= 1) {
        int t = (tid >= off) ? sc[tid - off] : 0;
        __syncthreads();
        sc[tid] += t;
        __syncthreads();
    }
    for (int b = tid; b < NBUCK; b += 512) {
        soff[b] = sc[b] - scnt[b];
        if (scnt[b] > 0) sbase[b] = atomicAdd(&g_bcur[b], scnt[b]);
    }
    __syncthreads();

    #pragma unroll
    for (int it = 0; it < 4; ++it) {
        if (s[it] >= 0) {
            int bd = d[it] >> NB_SHIFT;
            sbuf[soff[bd] + atomicAdd(&sput[bd], 1)] = make_int2(d[it], s[it]);
            int bs = s[it] >> NB_SHIFT;
            sbuf[soff[bs] + atomicAdd(&sput[bs], 1)] = make_int2(s[it], d[it]);
        }
    }
    __syncthreads();

    int total = sc[NBUCK - 1];
    for (int i = tid; i < total; i += 512) {
        int2 pr = sbuf[i];
        int  b  = pr.x >> NB_SHIFT;
        unsigned packed = ((unsigned)(pr.x & 255) << 24) | (unsigned)pr.y;
        g_stage[sbase[b] + (i - soff[b])] = packed;
    }
}

// ---- phase 2: per-bucket degree count + LDS scan (row ptrs, dis) + scatter ----
__global__ __launch_bounds__(512) void k_scatter(int n) {
    __shared__ int cols[P2CAP];
    __shared__ int cur[256];
    int b  = blockIdx.x;
    int v0 = b << NB_SHIFT;
    if (v0 >= n) return;
    int v1   = min(v0 + 256, n);
    int base = g_bbase[b];
    int len  = g_bbase[b + 1] - base;
    int tid  = threadIdx.x;

    // pass 1: per-node degree via LDS atomics (packed reads: 4B each)
    if (tid < 256) cur[tid] = 0;
    __syncthreads();
    for (int i = tid; i < len; i += 512) {
        unsigned p = g_stage[base + i];
        atomicAdd(&cur[p >> 24], 1);
    }
    __syncthreads();

    // inclusive Hillis-Steele scan of 256 degrees on first 256 lanes
    int d = (tid < 256) ? cur[tid] : 0;
    for (int off = 1; off < 256; off <<= 1) {
        int t = (tid < 256 && tid >= off) ? cur[tid - off] : 0;
        __syncthreads();
        if (tid < 256) cur[tid] += t;
        __syncthreads();
    }
    if (tid < 256) {
        int excl = cur[tid] - d;
        if (v0 + tid < v1) {
            g_row[v0 + tid] = base + excl;
            g_dis[v0 + tid] = 1.0f / sqrtf((float)d + 1.0f);
        }
    }
    if (tid == 0 && v1 == n) g_row[n] = base + len;
    __syncthreads();
    if (tid < 256) cur[tid] -= d;    // cur = exclusive prefix, reuse as cursor
    __syncthreads();

    // pass 2: scatter into LDS at final intra-bucket position
    for (int i = tid; i < len; i += 512) {
        unsigned p  = g_stage[base + i];
        int pos = atomicAdd(&cur[p >> 24], 1);
        int val = (int)(p & 0xFFFFFFu);
        if (pos < P2CAP) cols[pos] = val;
        else             g_col[base + pos] = val;
    }
    __syncthreads();
    int lim = len < P2CAP ? len : P2CAP;
    for (int i = tid; i < lim; i += 512)
        g_col[base + i] = cols[i];
}

// fp8 e4m3 single-value encode (low byte of pack)
__device__ __forceinline__ unsigned char enc_fp8(float v) {
    int w = __builtin_amdgcn_cvt_pk_fp8_f32(v, v, 0, false);
    return (unsigned char)(w & 0xff);
}

// fp8 message load: 4 features (4B) -> float4 via two v_cvt_pk_f32_fp8
__device__ __forceinline__ float4 ld_msg4(int node, int f4) {
    unsigned u = *(const unsigned*)(g_t8 + ((size_t)node << 6) + f4 * 4);
    f2v lo = __builtin_amdgcn_cvt_pk_f32_fp8((int)u, false);
    f2v hi = __builtin_amdgcn_cvt_pk_f32_fp8((int)u, true);
    return make_float4(lo.x, lo.y, hi.x, hi.y);
}

// ---- MFMA helpers (v_mfma_f32_16x16x16_f16, CDNA3-documented layouts) ----
// A: lane l holds A[l%16][4*(l>>4)+i]; B: B[4*(l>>4)+i][l%16];
// C/D: row = 4*(l>>4)+i, col = l%16  (m89-verified family).
// Wave w computes rows [16w,16w+16) x 64 cols as 4 accumulators.
// xh: [64][FP] f16 row-major (M x K); wt: [64][FP] = W^T (N x K).
__device__ __forceinline__ void mfma_strip(const _Float16 (*xh)[FP],
                                           const _Float16 (*wt)[FP],
                                           int wv, int lane, int klen,
                                           f32x4 acc[4]) {
    int r16 = lane & 15;
    int kg  = (lane >> 4) * 4;
    for (int k0 = 0; k0 < klen; k0 += 16) {
        h4 a = *(const h4*)&xh[wv * 16 + r16][k0 + kg];
        #pragma unroll
        for (int nt = 0; nt < 4; ++nt) {
            h4 b = *(const h4*)&wt[nt * 16 + r16][k0 + kg];
            acc[nt] = __builtin_amdgcn_mfma_f32_16x16x16f16(a, b, acc[nt], 0, 0, 0);
        }
    }
}

// vectorized wt staging from pre-transposed global table: 4 h4 per thread
__device__ __forceinline__ void stage_wt(_Float16 (*wt)[FP],
                                         const _Float16* __restrict__ src,
                                         int src_ld, int tid) {
    #pragma unroll
    for (int p = 0; p < 4; ++p) {
        int u  = p * 256 + tid;
        int nn = u >> 4;
        int kq = u & 15;
        *(h4*)&wt[nn][kq * 4] = *(const h4*)&src[(size_t)nn * src_ld + kq * 4];
    }
}

// ---- fused input layer + conv1 HW via MFMA ----
// t8 = fp8( dis * (relu(x@Win+bin) @ W1) ).  4 waves; 18.4KB LDS -> 8 blk/CU.
// Weights come PRE-TRANSPOSED f16 from g_wT (k_wprep) — vector staging.
__global__ __launch_bounds__(256) void k_inhw(const float* __restrict__ x,
                                              const float* __restrict__ bin, int n) {
    __shared__ _Float16 xh[TNI][FP];         // 9216 B
    __shared__ _Float16 wt[TNI][FP];         // 9216 B (transposed weights)
    int tid  = threadIdx.x;
    int lane = tid & 63;
    int wv   = tid >> 6;
    int n0   = blockIdx.x * TNI;

    f32x4 acc[4];
    #pragma unroll
    for (int nt = 0; nt < 4; ++nt) acc[nt] = (f32x4)0.0f;

    for (int c = 0; c < DIN / 64; ++c) {     // 3 chunks of K=64
        int k0 = c * 64;
        __syncthreads();
        // stage x chunk (64 rows x 64 cols, f32 -> f16)
        #pragma unroll
        for (int p = 0; p < 4; ++p) {
            int u   = p * 256 + tid;
            int row = u >> 4;
            int c4  = u & 15;
            float4 v = make_float4(0.f, 0.f, 0.f, 0.f);
            if (n0 + row < n)
                v = *(const float4*)(x + (size_t)(n0 + row) * DIN + k0 + c4 * 4);
            h4 hv = { (_Float16)v.x, (_Float16)v.y, (_Float16)v.z, (_Float16)v.w };
            *(h4*)&xh[row][c4 * 4] = hv;
        }
        stage_wt(wt, g_wT + k0, DIN, tid);   // Win^T cols [k0,k0+64)
        __syncthreads();
        mfma_strip(xh, wt, wv, lane, 64, acc);
    }

    // h = relu(acc + bin[col]); write f16 h into own wave's strip of xh
    __syncthreads();                         // all waves done reading xh/wt
    {
        int rg = (lane >> 4) * 4;
        #pragma unroll
        for (int nt = 0; nt < 4; ++nt) {
            int col = nt * 16 + (lane & 15);
            float bb = bin[col];
            #pragma unroll
            for (int i = 0; i < 4; ++i) {
                float hv = fmaxf(acc[nt][i] + bb, 0.f);
                xh[wv * 16 + rg + i][col] = (_Float16)hv;
            }
            acc[nt] = (f32x4)0.0f;           // reuse for phase 2
        }
    }
    stage_wt(wt, g_wT + WT_W1, HDIM, tid);   // W1^T
    __syncthreads();
    mfma_strip(xh, wt, wv, lane, 64, acc);

    // store fp8 messages: lane holds rows 4*(lane>>4)+i, col nt*16+(lane&15)
    {
        int rg = (lane >> 4) * 4;
        #pragma unroll
        for (int i = 0; i < 4; ++i) {
            int node = n0 + wv * 16 + rg + i;
            if (node < n) {
                float dv = g_dis[node];
                #pragma unroll
                for (int nt = 0; nt < 4; ++nt) {
                    int col = nt * 16 + (lane & 15);
                    g_t8[((size_t)node << 6) + col] = enc_fp8(dv * acc[nt][i]);
                }
            }
        }
    }
}

// ---- conv2 HW via MFMA: t8 = fp8( dis * (g_h @ W2) ) ----
__global__ __launch_bounds__(256) void k_hw2(int n) {
    __shared__ _Float16 xh[TNI][FP];
    __shared__ _Float16 wt[TNI][FP];
    int tid  = threadIdx.x;
    int lane = tid & 63;
    int wv   = tid >> 6;
    int n0   = blockIdx.x * TNI;

    // stage h tile (64 x 64 f32 -> f16)
    #pragma unroll
    for (int p = 0; p < 4; ++p) {
        int u   = p * 256 + tid;
        int row = u >> 4;
        int c4  = u & 15;
        float4 v = make_float4(0.f, 0.f, 0.f, 0.f);
        if (n0 + row < n)
            v = *(const float4*)(g_h + (size_t)(n0 + row) * HDIM + c4 * 4);
        h4 hv = { (_Float16)v.x, (_Float16)v.y, (_Float16)v.z, (_Float16)v.w };
        *(h4*)&xh[row][c4 * 4] = hv;
    }
    stage_wt(wt, g_wT + WT_W2, HDIM, tid);   // W2^T
    __syncthreads();

    f32x4 acc[4];
    #pragma unroll
    for (int nt = 0; nt < 4; ++nt) acc[nt] = (f32x4)0.0f;
    mfma_strip(xh, wt, wv, lane, 64, acc);

    {
        int rg = (lane >> 4) * 4;
        #pragma unroll
        for (int i = 0; i < 4; ++i) {
            int node = n0 + wv * 16 + rg + i;
            if (node < n) {
                float dv = g_dis[node];
                #pragma unroll
                for (int nt = 0; nt < 4; ++nt) {
                    int col = nt * 16 + (lane & 15);
                    g_t8[((size_t)node << 6) + col] = enc_fp8(dv * acc[nt][i]);
                }
            }
        }
    }
}

// CSR gather over row-major fp8 messages (64B rows).
// Lane layout: f4 = lane&15 (4 features via one 4B load), sub = lane>>4
// (edge slot 0..3) -> 4 edges per wave instruction. Main loop: 32 edges ->
// 8 independent table loads in flight per lane.
__global__ void k_gather(const float* __restrict__ b, int n) {
    int v = (blockIdx.x * blockDim.x + threadIdx.x) >> 6;
    if (v >= n) return;
    int lane = threadIdx.x & 63;
    int f4   = lane & 15;
    int sub  = lane >> 4;
    int beg = g_row[v], end = g_row[v + 1];
    float4 acc = make_float4(0.f, 0.f, 0.f, 0.f);
    int j = beg;
    for (; j + 32 <= end; j += 32) {
        int a0 = g_col[j + 0 + sub];
        int a1 = g_col[j + 4 + sub];
        int a2 = g_col[j + 8 + sub];
        int a3 = g_col[j + 12 + sub];
        int a4 = g_col[j + 16 + sub];
        int a5 = g_col[j + 20 + sub];
        int a6 = g_col[j + 24 + sub];
        int a7 = g_col[j + 28 + sub];
        float4 f0 = ld_msg4(a0, f4);
        float4 f1 = ld_msg4(a1, f4);
        float4 f2 = ld_msg4(a2, f4);
        float4 f3 = ld_msg4(a3, f4);
        float4 f4v = ld_msg4(a4, f4);
        float4 f5 = ld_msg4(a5, f4);
        float4 f6 = ld_msg4(a6, f4);
        float4 f7 = ld_msg4(a7, f4);
        acc.x += ((f0.x + f1.x) + (f2.x + f3.x)) + ((f4v.x + f5.x) + (f6.x + f7.x));
        acc.y += ((f0.y + f1.y) + (f2.y + f3.y)) + ((f4v.y + f5.y) + (f6.y + f7.y));
        acc.z += ((f0.z + f1.z) + (f2.z + f3.z)) + ((f4v.z + f5.z) + (f6.z + f7.z));
        acc.w += ((f0.w + f1.w) + (f2.w + f3.w)) + ((f4v.w + f5.w) + (f6.w + f7.w));
    }
    if (j + 16 <= end) {
        int a0 = g_col[j + 0 + sub];
        int a1 = g_col[j + 4 + sub];
        int a2 = g_col[j + 8 + sub];
        int a3 = g_col[j + 12 + sub];
        float4 f0 = ld_msg4(a0, f4);
        float4 f1 = ld_msg4(a1, f4);
        float4 f2 = ld_msg4(a2, f4);
        float4 f3 = ld_msg4(a3, f4);
        acc.x += (f0.x + f1.x) + (f2.x + f3.x);
        acc.y += (f0.y + f1.y) + (f2.y + f3.y);
        acc.z += (f0.z + f1.z) + (f2.z + f3.z);
        acc.w += (f0.w + f1.w) + (f2.w + f3.w);
        j += 16;
    }
    if (j + 8 <= end) {
        int a0 = g_col[j + 0 + sub];
        int a1 = g_col[j + 4 + sub];
        float4 f0 = ld_msg4(a0, f4);
        float4 f1 = ld_msg4(a1, f4);
        acc.x += f0.x + f1.x;
        acc.y += f0.y + f1.y;
        acc.z += f0.z + f1.z;
        acc.w += f0.w + f1.w;
        j += 8;
    }
    if (j + 4 <= end) {
        int a0 = g_col[j + sub];
        float4 f0 = ld_msg4(a0, f4);
        acc.x += f0.x; acc.y += f0.y; acc.z += f0.z; acc.w += f0.w;
        j += 4;
    }
    int r = end - j;
    if (sub < r) {
        int u = g_col[j + sub];
        float4 f0 = ld_msg4(u, f4);
        acc.x += f0.x; acc.y += f0.y; acc.z += f0.z; acc.w += f0.w;
    }
    acc.x += __shfl_xor(acc.x, 16, 64); acc.y += __shfl_xor(acc.y, 16, 64);
    acc.z += __shfl_xor(acc.z, 16, 64); acc.w += __shfl_xor(acc.w, 16, 64);
    acc.x += __shfl_xor(acc.x, 32, 64); acc.y += __shfl_xor(acc.y, 32, 64);
    acc.z += __shfl_xor(acc.z, 32, 64); acc.w += __shfl_xor(acc.w, 32, 64);
    if (sub == 0) {
        float4 sf = ld_msg4(v, f4);     // self term
        float dv  = g_dis[v];
        float4 bb = *((const float4*)b + f4);
        float4 o;
        o.x = fmaxf(dv * (acc.x + sf.x) + bb.x, 0.f);
        o.y = fmaxf(dv * (acc.y + sf.y) + bb.y, 0.f);
        o.z = fmaxf(dv * (acc.z + sf.z) + bb.z, 0.f);
        o.w = fmaxf(dv * (acc.w + sf.w) + bb.w, 0.f);
        *((float4*)(g_h + (size_t)v * HDIM) + f4) = o;
    }
}

// fused mean-pool + MLP head + log_softmax; 4 waves per graph
__global__ void k_poolhead(const float* __restrict__ Wf1, const float* __restrict__ bf1,
                           const float* __restrict__ Wf2, const float* __restrict__ bf2,
                           float* __restrict__ out) {
    __shared__ float ps[4][HDIM];
    __shared__ float p[HDIM];
    __shared__ float z[DOUTD];
    int g   = blockIdx.x;
    int tid = threadIdx.x;
    int f   = tid & 63, q = tid >> 6;
    int beg = g_gptr[g], end = g_gptr[g + 1];
    float s = 0.0f;
    for (int i = beg + q; i < end; i += 4)
        s += __builtin_nontemporal_load(&g_h[(size_t)i * HDIM + f]);
    ps[q][f] = s;
    __syncthreads();
    if (tid < HDIM) {
        float cnt = fmaxf((float)(end - beg), 1.0f);
        p[tid] = (ps[0][tid] + ps[1][tid] + ps[2][tid] + ps[3][tid]) / cnt;
    }
    __syncthreads();
    if (tid < DOUTD) {
        float a = bf1[tid];
        for (int k = 0; k < HDIM; ++k)
            a += p[k] * Wf1[k * DOUTD + tid];
        z[tid] = fmaxf(a, 0.0f);
    }
    __syncthreads();
    if (tid == 0) {
        float l0 = bf2[0], l1 = bf2[1];
        for (int k = 0; k < DOUTD; ++k) {
            l0 += z[k] * Wf2[k * NCLS + 0];
            l1 += z[k] * Wf2[k * NCLS + 1];
        }
        float m   = fmaxf(l0, l1);
        float lse = m + logf(expf(l0 - m) + expf(l1 - m));
        out[g * NCLS + 0] = l0 - lse;
        out[g * NCLS + 1] = l1 - lse;
    }
}

extern "C" void kernel_launch(void* const* d_in, const int* in_sizes, int n_in,
                              void* d_out, int out_size, void* d_ws, size_t ws_size,
                              hipStream_t stream) {
    (void)d_ws; (void)ws_size; (void)out_size;

    const float* x   = (const float*)d_in[0];
    const int*   ei  = (const int*)d_in[1];
    const int*   bat = (const int*)d_in[2];

    const float* wp[10] = {nullptr};
    int wi = 0;
    for (int i = 3; i < n_in && wi < 10; ++i) {
        if (in_sizes[i] == 1) continue;
        wp[wi++] = (const float*)d_in[i];
    }
    const float* W_in = wp[0];
    const float* b_in = wp[1];
    const float* W1   = wp[2];
    const float* b1   = wp[3];
    const float* W2   = wp[4];
    const float* b2   = wp[5];
    const float* Wf1  = wp[6];
    const float* bf1  = wp[7];
    const float* Wf2  = wp[8];
    const float* bf2  = wp[9];

    const int n = in_sizes[0] / DIN;
    const int E = in_sizes[1] / 2;

    const int B = 256;
    int gNH    = (int)(((long long)n * HDIM + B - 1) / B);
    int gTile  = (n + TNI - 1) / TNI;
    int gStage = (E + T1E - 1) / T1E;
    int gMeta  = 1 + (n + 1 + 511) / 512;
    int gWprep = (WT_W2 + 64 * HDIM + 255) / 256;

    k_wprep<<<gWprep, 256, 0, stream>>>(W_in, W1, W2);
    k_count<<<512, 256, 0, stream>>>(ei, E);
    k_meta<<<gMeta, 512, 0, stream>>>(bat, n);

    k_stage<<<gStage, 512, 0, stream>>>(ei, E);
    k_scatter<<<NBUCK, 512, 0, stream>>>(n);

    // fused input layer + conv1 HW (MFMA, pre-transposed weights)
    k_inhw<<<gTile, 256, 0, stream>>>(x, b_in, n);
    k_gather<<<gNH, B, 0, stream>>>(b1, n);

    // conv 2 (MFMA)
    k_hw2<<<gTile, 256, 0, stream>>>(n);
    k_gather<<<gNH, B, 0, stream>>>(b2, n);

    k_poolhead<<<NGRAPH, 256, 0, stream>>>(Wf1, bf1, Wf2, bf2, (float*)d_out);
}